// Round 2
// baseline (875.405 us; speedup 1.0000x reference)
//
#include <hip/hip_runtime.h>

// ---------------- workspace layout (byte offsets, all 256-aligned) ----------
static constexpr size_t OFF_XT = 0;          // xT  [3][32][32][64] f32   786432 B
static constexpr size_t OFF_H1 = 786432;     // h1  [18][28][28][64]      3612672 B  (dead after s2; reused as h5b)
static constexpr size_t OFF_H2 = 4399104;    // h2  [51][14][14][64]      2558976 B
static constexpr size_t OFF_H3 = 6958080;    // h3  [255][5][5][2][2][64] 6528000 B  (pool-permuted)
static constexpr size_t OFF_H4 = 13486080;   // h4  [515][5][5][64]       3296000 B
static constexpr size_t OFF_H5 = 16782080;   // h5a [2500][64] PARTIAL    640000 B
static constexpr size_t OFF_H5B = OFF_H1;    // h5b [2500][64] PARTIAL    (aliases dead h1)
static constexpr size_t OFF_H6 = 17422080;   // h6T [120][64] PRE-ACT     30720 B (zeroed in setup; atomicAdd in s6)
static constexpr size_t OFF_H7 = 17452800;   // h7T [84][64]              21504 B
static constexpr size_t OFF_M1 = 17474304;   // int src1[51][4]           1024 B
static constexpr size_t OFF_M2 = 17475328;   // Meta2[536]                8704 B
static constexpr size_t OFF_W2 = 17484032;   // float W2[536][51]         109568 B
static constexpr size_t OFF_BAR = 17593600;  // uint bar[1088]: 32 leaf cnts (stride 32) + root + release

struct Meta2 { int g; int special; float wj; int valid; };

__device__ inline void scan_ijk(int F, int ncpf, int g, int& oi, int& oj, int& ok) {
  int cnt = 0;
  for (int i = 0; i < F; ++i)
    for (int j = 0; j < ncpf; ++j) {
      int ks = (j == 0) ? i : i + 1;
      for (int k = ks; k < F; ++k) {
        if (cnt == g) { oi = i; oj = j; ok = k; return; }
        ++cnt;
      }
    }
  oi = 0; oj = 0; ok = 0;
}

__device__ inline float4 f4fma(float4 v, float w, float4 a) {
  a.x = fmaf(v.x, w, a.x); a.y = fmaf(v.y, w, a.y);
  a.z = fmaf(v.z, w, a.z); a.w = fmaf(v.w, w, a.w);
  return a;
}

// ---------------------------------------------------------------------------
// Custom two-level grid barrier (monotonic epochs, no reset needed within a
// launch; counters zeroed by the setup kernel each iteration).
//   bar[l*32]   : leaf counter l (l = 0..31), one cacheline apart
//   bar[1024]   : root counter
//   bar[1056]   : release word (stores latest completed epoch)
// Requires all blocks co-resident (cooperative launch).
// ---------------------------------------------------------------------------
__device__ inline void grid_barrier(unsigned int* bar, int epoch) {
  __syncthreads();
  if (threadIdx.x == 0) {
    __threadfence();                       // release: publish this block's stage writes
    const int nb = (int)gridDim.x;
    unsigned int* rootcnt = bar + 1024;
    unsigned int* release = bar + 1056;
    int leaf = blockIdx.x & 31;
    int bpl = (nb + 31 - leaf) >> 5;       // blocks in this leaf
    unsigned int v = __hip_atomic_fetch_add(&bar[leaf * 32], 1u,
                                            __ATOMIC_ACQ_REL, __HIP_MEMORY_SCOPE_AGENT);
    if ((int)v == epoch * bpl - 1) {       // last arriver in leaf
      int nl = nb < 32 ? nb : 32;
      unsigned int r = __hip_atomic_fetch_add(rootcnt, 1u,
                                              __ATOMIC_ACQ_REL, __HIP_MEMORY_SCOPE_AGENT);
      if ((int)r == epoch * nl - 1) {      // last leaf overall -> release
        __hip_atomic_store(release, (unsigned int)epoch,
                           __ATOMIC_RELEASE, __HIP_MEMORY_SCOPE_AGENT);
      }
    }
    while (__hip_atomic_load(release, __ATOMIC_ACQUIRE, __HIP_MEMORY_SCOPE_AGENT)
           < (unsigned int)epoch) {
      __builtin_amdgcn_s_sleep(1);
    }
    __threadfence();                       // acquire: see all other blocks' writes
  }
  __syncthreads();
}

// ===========================================================================
// Setup kernel (ordinary launch): xT transpose, pc1/pc2 metadata, zero h6,
// zero barrier counters. Stream order syncs it before the mega kernel.
// grid(235) block(256)
// ===========================================================================
__global__ void k0_setup(const float* __restrict__ x, const float* __restrict__ pc2_w,
                         float* ws) {
  int bx = blockIdx.x, tid = threadIdx.x;
  if (bx < 96) {
    __shared__ float t[64][33];
    int c = bx >> 5, y = bx & 31;
    for (int r = 0; r < 8; ++r) {
      int b = r * 8 + (tid >> 5), xx = tid & 31;
      t[b][xx] = x[((b * 3 + c) * 32 + y) * 32 + xx];
    }
    __syncthreads();
    float* xT = ws + OFF_XT / 4;
    for (int r = 0; r < 8; ++r) {
      int xx = r * 4 + (tid >> 6), b = tid & 63;
      xT[((c * 32 + y) * 32 + xx) * 64 + b] = t[b][xx];
    }
  } else if (bx == 96) {
    if (tid < 51) {
      int i, j, k; scan_ijk(6, 3, tid, i, j, k);
      int* src1 = (int*)((char*)ws + OFF_M1);
      for (int p = 0; p < 3; ++p)
        src1[tid * 4 + p] = (p == j) ? (i * 3 + j) : (k * 3 + p);
    }
  } else if (bx < 204) {
    int idx = (bx - 97) * 256 + tid;     // one thread per (s,p), 536*51 = 27336
    if (idx < 536 * 51) {
      int s = idx / 51, p = idx - s * 51;
      int k, base;
      if (s < 8)        { k = 0; base = 0; }
      else if (s < 64)  { k = 1; base = 8; }
      else if (s < 168) { k = 2; base = 64; }
      else if (s < 328) { k = 3; base = 168; }
      else              { k = 4; base = 328; }
      int id2 = s - base;
      int cnt = 51 * k + 1;
      Meta2* m2 = (Meta2*)((char*)ws + OFF_M2);
      float* W2 = (float*)((char*)ws + OFF_W2);
      if (id2 < cnt) {
        int i, j;
        if (id2 <= k) { i = id2; j = 0; }
        else { int t2 = id2 - (k + 1); i = t2 / 50; j = t2 - i * 50 + 1; }
        int off = 205 * i - 51 * ((i * (i - 1)) >> 1);
        int g = (j == 0) ? (off + (k - i))
                         : (off + (5 - i) + (j - 1) * (4 - i) + (k - i - 1));
        W2[s * 51 + p] = (p == j) ? 0.f : pc2_w[g * 51 + p];
        if (p == 0) {
          m2[s].g = g; m2[s].special = i * 51 + j;
          m2[s].wj = pc2_w[g * 51 + j]; m2[s].valid = 1;
        }
      } else {
        W2[s * 51 + p] = 0.f;
        if (p == 0) { m2[s].g = 0; m2[s].special = 0; m2[s].wj = 0.f; m2[s].valid = 0; }
      }
    }
  } else if (bx < 234) {
    int idx = (bx - 204) * 256 + tid;    // zero h6: 120*64 = 7680 floats
    if (idx < 7680) (ws + OFF_H6 / 4)[idx] = 0.f;
  } else {
    // zero barrier region: 1088 uints
    unsigned int* bar = (unsigned int*)((char*)ws + OFF_BAR);
    for (int i = tid; i < 1088; i += 256) bar[i] = 0u;
  }
}

// ===========================================================================
// MEGA: stages 1..8 as one persistent cooperative kernel, 7 custom barriers.
// ===========================================================================
struct MegaParams {
  const float* dw1_w; const float* dw1_b;
  const float* pc1_w; const float* pc1_b;
  const float* dw2_w; const float* dw2_b;
  const float* pc2_b;
  const float* oo_w;  const float* oo_b;
  const float* fc1_w; const float* fc1_b;
  const float* fc2_w; const float* fc2_b;
  const float* fc3_w; const float* fc3_b;
  float* ws; float* out;
};

__global__ void __launch_bounds__(256, 4) mega(MegaParams prm) {
  float* ws = prm.ws;
  unsigned int* bar = (unsigned int*)((char*)ws + OFF_BAR);
  const int nb = gridDim.x;
  const int tid = threadIdx.x;
  const int lane = tid & 63;
  const int wv = __builtin_amdgcn_readfirstlane(tid >> 6);

  __shared__ float red[4][4][64];  // stages 5,6
  __shared__ float red2[4][64];    // stages 7,8

  // ---- stage 1: dw1 5x5 groups=3 (3528 wave-tasks) ----
  {
    const float* xT = ws + OFF_XT / 4;
    float* h1 = ws + OFF_H1 / 4;
    int sub = lane >> 4, b4 = (lane & 15) * 4;
    for (int task = blockIdx.x * 4 + wv; task < 3528; task += nb * 4) {
      int o = task / 196, rem = task - o * 196;
      int y = rem / 7, xo = (rem - y * 7) * 4 + sub;
      int c = o / 6;
      float bb = prm.dw1_b[o];
      float4 acc = {bb, bb, bb, bb};
      const float* src = xT + ((c * 32 + y) * 32 + xo) * 64 + b4;
      #pragma unroll
      for (int ky = 0; ky < 5; ++ky)
        #pragma unroll
        for (int kx = 0; kx < 5; ++kx) {
          float4 v = *(const float4*)(src + (ky * 32 + kx) * 64);
          acc = f4fma(v, prm.dw1_w[o * 25 + ky * 5 + kx], acc);
        }
      *(float4*)(h1 + ((o * 28 + y) * 28 + xo) * 64 + b4) = acc;
    }
  }
  grid_barrier(bar, 1);

  // ---- stage 2: pc1 gather + relu + pool (2499 wave-tasks) ----
  {
    const float* h1 = ws + OFF_H1 / 4;
    const int* src1 = (const int*)((const char*)ws + OFF_M1);
    float* h2 = ws + OFF_H2 / 4;
    int sub = lane >> 4, b4 = (lane & 15) * 4;
    for (int task = blockIdx.x * 4 + wv; task < 2499; task += nb * 4) {
      int g = task / 49, pc = task - g * 49;
      int pp = pc * 4 + sub;
      int py = pp / 14, px = pp - py * 14;
      int s0 = src1[g * 4 + 0], s1 = src1[g * 4 + 1], s2 = src1[g * 4 + 2];
      float w0 = prm.pc1_w[g * 3 + 0], w1 = prm.pc1_w[g * 3 + 1];
      float w2 = prm.pc1_w[g * 3 + 2], bb = prm.pc1_b[g];
      float4 m = {0.f, 0.f, 0.f, 0.f};
      #pragma unroll
      for (int dy = 0; dy < 2; ++dy)
        #pragma unroll
        for (int dx = 0; dx < 2; ++dx) {
          int y = py * 2 + dy, xx = px * 2 + dx;
          float4 a = {bb, bb, bb, bb};
          a = f4fma(*(const float4*)(h1 + ((s0 * 28 + y) * 28 + xx) * 64 + b4), w0, a);
          a = f4fma(*(const float4*)(h1 + ((s1 * 28 + y) * 28 + xx) * 64 + b4), w1, a);
          a = f4fma(*(const float4*)(h1 + ((s2 * 28 + y) * 28 + xx) * 64 + b4), w2, a);
          m.x = fmaxf(m.x, a.x); m.y = fmaxf(m.y, a.y);
          m.z = fmaxf(m.z, a.z); m.w = fmaxf(m.w, a.w);
        }
      *(float4*)(h2 + ((g * 14 + py) * 14 + px) * 64 + b4) = m;
    }
  }
  grid_barrier(bar, 2);

  // ---- stage 3: dw2 5x5 groups=51, pool-permuted out (6375 wave-tasks) ----
  {
    const float* h2 = ws + OFF_H2 / 4;
    float* h3 = ws + OFF_H3 / 4;
    int sub = lane >> 4, b4 = (lane & 15) * 4;
    for (int task = blockIdx.x * 4 + wv; task < 6375; task += nb * 4) {
      int o = task / 25, pc = task - o * 25;
      int pp = pc * 4 + sub;
      int y = pp / 10, xo = pp - y * 10;
      int c = o / 5;
      float bb = prm.dw2_b[o];
      float4 acc = {bb, bb, bb, bb};
      const float* src = h2 + ((c * 14 + y) * 14 + xo) * 64 + b4;
      #pragma unroll
      for (int ky = 0; ky < 5; ++ky)
        #pragma unroll
        for (int kx = 0; kx < 5; ++kx) {
          float4 v = *(const float4*)(src + (ky * 14 + kx) * 64);
          acc = f4fma(v, prm.dw2_w[o * 25 + ky * 5 + kx], acc);
        }
      int py = y >> 1, dy = y & 1, px = xo >> 1, dx = xo & 1;
      *(float4*)(h3 + ((o * 25 + py * 5 + px) * 4 + dy * 2 + dx) * 64 + b4) = acc;
    }
  }
  grid_barrier(bar, 3);

  // ---- stage 4: pc2 dense 51-dot + rank-1 correction + relu + pool (1675 block-tasks) ----
  {
    const float* h3 = ws + OFF_H3 / 4;
    const float* W2 = (const float*)((const char*)ws + OFF_W2);
    const Meta2* m2 = (const Meta2*)((const char*)ws + OFF_M2);
    float* h4 = ws + OFF_H4 / 4;
    for (int bt = blockIdx.x; bt < 1675; bt += nb) {
      int chunk = bt / 25, pyx = bt - chunk * 25;
      int k;
      if (chunk < 1) k = 0; else if (chunk < 8) k = 1; else if (chunk < 21) k = 2;
      else if (chunk < 41) k = 3; else k = 4;
      int s0 = chunk * 8 + wv * 2;
      float acc[2][4];
      #pragma unroll
      for (int m = 0; m < 2; ++m)
        #pragma unroll
        for (int q = 0; q < 4; ++q) acc[m][q] = 0.f;
      const float* hb = h3 + (size_t)(k * 51 * 100 + pyx * 4) * 64 + lane;
      const float* wr0 = W2 + (s0 + 0) * 51;
      const float* wr1 = W2 + (s0 + 1) * 51;
      for (int p = 0; p < 51; ++p) {
        float v0 = hb[p * 6400 + 0];
        float v1 = hb[p * 6400 + 64];
        float v2 = hb[p * 6400 + 128];
        float v3 = hb[p * 6400 + 192];
        float wa = wr0[p], wb = wr1[p];
        acc[0][0] = fmaf(v0, wa, acc[0][0]);
        acc[0][1] = fmaf(v1, wa, acc[0][1]);
        acc[0][2] = fmaf(v2, wa, acc[0][2]);
        acc[0][3] = fmaf(v3, wa, acc[0][3]);
        acc[1][0] = fmaf(v0, wb, acc[1][0]);
        acc[1][1] = fmaf(v1, wb, acc[1][1]);
        acc[1][2] = fmaf(v2, wb, acc[1][2]);
        acc[1][3] = fmaf(v3, wb, acc[1][3]);
      }
      #pragma unroll
      for (int m = 0; m < 2; ++m) {
        Meta2 mm = m2[s0 + m];
        if (!mm.valid) continue;
        const float* hs = h3 + (size_t)(mm.special * 100 + pyx * 4) * 64 + lane;
        float bb = prm.pc2_b[mm.g];
        float r0 = fmaf(hs[0],   mm.wj, acc[m][0]) + bb;
        float r1 = fmaf(hs[64],  mm.wj, acc[m][1]) + bb;
        float r2 = fmaf(hs[128], mm.wj, acc[m][2]) + bb;
        float r3 = fmaf(hs[192], mm.wj, acc[m][3]) + bb;
        float r = fmaxf(fmaxf(r0, r1), fmaxf(r2, r3));
        h4[(mm.g * 25 + pyx) * 64 + lane] = fmaxf(r, 0.f);
      }
    }
  }
  grid_barrier(bar, 4);

  // ---- stage 5: oo partials 515->100 (1250 block-tasks) ----
  {
    const float* h4 = ws + OFF_H4 / 4;
    for (int bt = blockIdx.x; bt < 1250; bt += nb) {
      int pyx = bt % 25, og = (bt / 25) % 25, ks = bt / 625;
      int kb = ks ? 258 : 0;
      int kn = ks ? 257 : 258;
      int q = kn >> 2, r = kn & 3;
      int base = __builtin_amdgcn_readfirstlane(kb + wv * q + (wv < r ? wv : r));
      int n = q + (wv < r ? 1 : 0);
      const float* w0 = prm.oo_w + (og * 4 + 0) * 515;
      const float* w1 = prm.oo_w + (og * 4 + 1) * 515;
      const float* w2 = prm.oo_w + (og * 4 + 2) * 515;
      const float* w3 = prm.oo_w + (og * 4 + 3) * 515;
      const float* hp = h4 + pyx * 64 + lane;
      float a0 = 0.f, a1 = 0.f, a2 = 0.f, a3 = 0.f;
      #pragma unroll 4
      for (int i = 0; i < n; ++i) {
        int c = base + i;
        float v = hp[c * 1600];
        a0 = fmaf(v, w0[c], a0);
        a1 = fmaf(v, w1[c], a1);
        a2 = fmaf(v, w2[c], a2);
        a3 = fmaf(v, w3[c], a3);
      }
      red[wv][0][lane] = a0; red[wv][1][lane] = a1;
      red[wv][2][lane] = a2; red[wv][3][lane] = a3;
      __syncthreads();
      if (wv == 0) {
        float* h5p = ws + (ks ? OFF_H5B : OFF_H5) / 4;
        #pragma unroll
        for (int m = 0; m < 4; ++m) {
          float s = red[0][m][lane] + red[1][m][lane] + red[2][m][lane] + red[3][m][lane];
          h5p[((og * 4 + m) * 25 + pyx) * 64 + lane] = s;
        }
      }
      __syncthreads();
    }
  }
  grid_barrier(bar, 5);

  // ---- stage 6: fc1 partials, atomicAdd into h6 (480 block-tasks) ----
  {
    const float* h5a = ws + OFF_H5 / 4;
    const float* h5b = ws + OFF_H5B / 4;
    float* h6 = ws + OFF_H6 / 4;
    for (int bt = blockIdx.x; bt < 480; bt += nb) {
      int og = bt % 30, ks = bt / 30;
      int kb = ks * 156 + (ks < 4 ? ks : 4);
      int kn = 156 + (ks < 4 ? 1 : 0);
      int q = kn >> 2, r = kn & 3;
      int base = __builtin_amdgcn_readfirstlane(kb + wv * q + (wv < r ? wv : r));
      int n = q + (wv < r ? 1 : 0);
      const float* w0 = prm.fc1_w + (og * 4 + 0) * 2500;
      const float* w1 = prm.fc1_w + (og * 4 + 1) * 2500;
      const float* w2 = prm.fc1_w + (og * 4 + 2) * 2500;
      const float* w3 = prm.fc1_w + (og * 4 + 3) * 2500;
      float a0 = 0.f, a1 = 0.f, a2 = 0.f, a3 = 0.f;
      #pragma unroll 4
      for (int i = 0; i < n; ++i) {
        int k = base + i;
        float v = fmaxf(h5a[k * 64 + lane] + h5b[k * 64 + lane] + prm.oo_b[k / 25], 0.f);
        a0 = fmaf(v, w0[k], a0);
        a1 = fmaf(v, w1[k], a1);
        a2 = fmaf(v, w2[k], a2);
        a3 = fmaf(v, w3[k], a3);
      }
      red[wv][0][lane] = a0; red[wv][1][lane] = a1;
      red[wv][2][lane] = a2; red[wv][3][lane] = a3;
      __syncthreads();
      if (wv == 0) {
        #pragma unroll
        for (int m = 0; m < 4; ++m) {
          float s = red[0][m][lane] + red[1][m][lane] + red[2][m][lane] + red[3][m][lane];
          atomicAdd(&h6[(og * 4 + m) * 64 + lane], s);
        }
      }
      __syncthreads();
    }
  }
  grid_barrier(bar, 6);

  // ---- stage 7: fc2 120->84 + relu (84 block-tasks) ----
  {
    const float* h6 = ws + OFF_H6 / 4;
    float* h7 = ws + OFF_H7 / 4;
    for (int o = blockIdx.x; o < 84; o += nb) {
      float acc = 0.f;
      int i0 = wv * 30;
      #pragma unroll 5
      for (int i = i0; i < i0 + 30; ++i) {
        float v = fmaxf(h6[i * 64 + lane] + prm.fc1_b[i], 0.f);
        acc = fmaf(v, prm.fc2_w[o * 120 + i], acc);
      }
      red2[wv][lane] = acc;
      __syncthreads();
      if (tid < 64) {
        float s = red2[0][lane] + red2[1][lane] + red2[2][lane] + red2[3][lane] + prm.fc2_b[o];
        h7[o * 64 + lane] = fmaxf(s, 0.f);
      }
      __syncthreads();
    }
  }
  grid_barrier(bar, 7);

  // ---- stage 8: fc3 84->10, write output (10 block-tasks) ----
  {
    const float* h7 = ws + OFF_H7 / 4;
    for (int o = blockIdx.x; o < 10; o += nb) {
      float acc = 0.f;
      int i0 = wv * 21;
      #pragma unroll 7
      for (int i = i0; i < i0 + 21; ++i)
        acc = fmaf(h7[i * 64 + lane], prm.fc3_w[o * 84 + i], acc);
      red2[wv][lane] = acc;
      __syncthreads();
      if (tid < 64) {
        float s = red2[0][lane] + red2[1][lane] + red2[2][lane] + red2[3][lane] + prm.fc3_b[o];
        prm.out[lane * 10 + o] = s;
      }
      __syncthreads();
    }
  }
}

// ===========================================================================
// Fallback path: original 9-kernel pipeline (used only if cooperative launch
// is rejected). k0_setup above doubles as its setup kernel (grid 234).
// ===========================================================================
__global__ void __launch_bounds__(256) k1_dw1(const float* __restrict__ w,
                                              const float* __restrict__ bias, float* ws) {
  const float* xT = ws + OFF_XT / 4;
  float* h1 = ws + OFF_H1 / 4;
  int task = blockIdx.x * 4 + __builtin_amdgcn_readfirstlane(threadIdx.y);
  int l = threadIdx.x;
  int sub = l >> 4, b4 = (l & 15) * 4;
  int o = task / 196, rem = task - o * 196;
  int y = rem / 7, xo = (rem - y * 7) * 4 + sub;
  int c = o / 6;
  float bb = bias[o];
  float4 acc = {bb, bb, bb, bb};
  const float* src = xT + ((c * 32 + y) * 32 + xo) * 64 + b4;
  #pragma unroll
  for (int ky = 0; ky < 5; ++ky)
    #pragma unroll
    for (int kx = 0; kx < 5; ++kx) {
      float4 v = *(const float4*)(src + (ky * 32 + kx) * 64);
      acc = f4fma(v, w[o * 25 + ky * 5 + kx], acc);
    }
  *(float4*)(h1 + ((o * 28 + y) * 28 + xo) * 64 + b4) = acc;
}

__global__ void __launch_bounds__(256) k2_pc1(const float* __restrict__ w,
                                              const float* __restrict__ bias, float* ws) {
  const float* h1 = ws + OFF_H1 / 4;
  const int* src1 = (const int*)((const char*)ws + OFF_M1);
  float* h2 = ws + OFF_H2 / 4;
  int task = blockIdx.x * 4 + __builtin_amdgcn_readfirstlane(threadIdx.y);
  if (task >= 2499) return;
  int l = threadIdx.x;
  int sub = l >> 4, b4 = (l & 15) * 4;
  int g = task / 49, pc = task - g * 49;
  int pp = pc * 4 + sub;
  int py = pp / 14, px = pp - py * 14;
  int s0 = src1[g * 4 + 0], s1 = src1[g * 4 + 1], s2 = src1[g * 4 + 2];
  float w0 = w[g * 3 + 0], w1 = w[g * 3 + 1], w2 = w[g * 3 + 2], bb = bias[g];
  float4 m = {0.f, 0.f, 0.f, 0.f};
  #pragma unroll
  for (int dy = 0; dy < 2; ++dy)
    #pragma unroll
    for (int dx = 0; dx < 2; ++dx) {
      int y = py * 2 + dy, xx = px * 2 + dx;
      float4 a = {bb, bb, bb, bb};
      a = f4fma(*(const float4*)(h1 + ((s0 * 28 + y) * 28 + xx) * 64 + b4), w0, a);
      a = f4fma(*(const float4*)(h1 + ((s1 * 28 + y) * 28 + xx) * 64 + b4), w1, a);
      a = f4fma(*(const float4*)(h1 + ((s2 * 28 + y) * 28 + xx) * 64 + b4), w2, a);
      m.x = fmaxf(m.x, a.x); m.y = fmaxf(m.y, a.y);
      m.z = fmaxf(m.z, a.z); m.w = fmaxf(m.w, a.w);
    }
  *(float4*)(h2 + ((g * 14 + py) * 14 + px) * 64 + b4) = m;
}

__global__ void __launch_bounds__(256) k3_dw2(const float* __restrict__ w,
                                              const float* __restrict__ bias, float* ws) {
  const float* h2 = ws + OFF_H2 / 4;
  float* h3 = ws + OFF_H3 / 4;
  int task = blockIdx.x * 4 + __builtin_amdgcn_readfirstlane(threadIdx.y);
  if (task >= 6375) return;
  int l = threadIdx.x;
  int sub = l >> 4, b4 = (l & 15) * 4;
  int o = task / 25, pc = task - o * 25;
  int p = pc * 4 + sub;
  int y = p / 10, xo = p - y * 10;
  int c = o / 5;
  float bb = bias[o];
  float4 acc = {bb, bb, bb, bb};
  const float* src = h2 + ((c * 14 + y) * 14 + xo) * 64 + b4;
  #pragma unroll
  for (int ky = 0; ky < 5; ++ky)
    #pragma unroll
    for (int kx = 0; kx < 5; ++kx) {
      float4 v = *(const float4*)(src + (ky * 14 + kx) * 64);
      acc = f4fma(v, w[o * 25 + ky * 5 + kx], acc);
    }
  int py = y >> 1, dy = y & 1, px = xo >> 1, dx = xo & 1;
  *(float4*)(h3 + ((o * 25 + py * 5 + px) * 4 + dy * 2 + dx) * 64 + b4) = acc;
}

__global__ void __launch_bounds__(256) k4_pc2(const float* __restrict__ bias, float* ws) {
  const float* h3 = ws + OFF_H3 / 4;
  const float* W2 = (const float*)((const char*)ws + OFF_W2);
  const Meta2* m2 = (const Meta2*)((const char*)ws + OFF_M2);
  float* h4 = ws + OFF_H4 / 4;
  int b = threadIdx.x;
  int wv = __builtin_amdgcn_readfirstlane(threadIdx.y);
  int pyx = blockIdx.x;
  int chunk = blockIdx.y;
  int k;
  if (chunk < 1) k = 0; else if (chunk < 8) k = 1; else if (chunk < 21) k = 2;
  else if (chunk < 41) k = 3; else k = 4;
  int s0 = chunk * 8 + wv * 2;
  float acc[2][4];
  #pragma unroll
  for (int m = 0; m < 2; ++m)
    #pragma unroll
    for (int q = 0; q < 4; ++q) acc[m][q] = 0.f;
  const float* hb = h3 + (size_t)(k * 51 * 100 + pyx * 4) * 64 + b;
  const float* wr0 = W2 + (s0 + 0) * 51;
  const float* wr1 = W2 + (s0 + 1) * 51;
  for (int p = 0; p < 51; ++p) {
    float v0 = hb[p * 6400 + 0];
    float v1 = hb[p * 6400 + 64];
    float v2 = hb[p * 6400 + 128];
    float v3 = hb[p * 6400 + 192];
    float wa = wr0[p], wb = wr1[p];
    acc[0][0] = fmaf(v0, wa, acc[0][0]);
    acc[0][1] = fmaf(v1, wa, acc[0][1]);
    acc[0][2] = fmaf(v2, wa, acc[0][2]);
    acc[0][3] = fmaf(v3, wa, acc[0][3]);
    acc[1][0] = fmaf(v0, wb, acc[1][0]);
    acc[1][1] = fmaf(v1, wb, acc[1][1]);
    acc[1][2] = fmaf(v2, wb, acc[1][2]);
    acc[1][3] = fmaf(v3, wb, acc[1][3]);
  }
  #pragma unroll
  for (int m = 0; m < 2; ++m) {
    Meta2 mm = m2[s0 + m];
    if (!mm.valid) continue;
    const float* hs = h3 + (size_t)(mm.special * 100 + pyx * 4) * 64 + b;
    float bb = bias[mm.g];
    float r0 = fmaf(hs[0],   mm.wj, acc[m][0]) + bb;
    float r1 = fmaf(hs[64],  mm.wj, acc[m][1]) + bb;
    float r2 = fmaf(hs[128], mm.wj, acc[m][2]) + bb;
    float r3 = fmaf(hs[192], mm.wj, acc[m][3]) + bb;
    float r = fmaxf(fmaxf(r0, r1), fmaxf(r2, r3));
    h4[(mm.g * 25 + pyx) * 64 + b] = fmaxf(r, 0.f);
  }
}

__global__ void __launch_bounds__(256) k5_oo(const float* __restrict__ w, float* ws) {
  const float* h4 = ws + OFF_H4 / 4;
  __shared__ float red[4][4][64];
  int lane = threadIdx.x;
  int wv = __builtin_amdgcn_readfirstlane(threadIdx.y);
  int pyx = blockIdx.x, og = blockIdx.y, ks = blockIdx.z;
  int kb = ks ? 258 : 0;
  int kn = ks ? 257 : 258;
  int q = kn >> 2, r = kn & 3;
  int base = __builtin_amdgcn_readfirstlane(kb + wv * q + (wv < r ? wv : r));
  int n = q + (wv < r ? 1 : 0);
  const float* w0 = w + (og * 4 + 0) * 515;
  const float* w1 = w + (og * 4 + 1) * 515;
  const float* w2 = w + (og * 4 + 2) * 515;
  const float* w3 = w + (og * 4 + 3) * 515;
  const float* hp = h4 + pyx * 64 + lane;
  float a0 = 0.f, a1 = 0.f, a2 = 0.f, a3 = 0.f;
  #pragma unroll 4
  for (int i = 0; i < n; ++i) {
    int c = base + i;
    float v = hp[c * 1600];
    a0 = fmaf(v, w0[c], a0);
    a1 = fmaf(v, w1[c], a1);
    a2 = fmaf(v, w2[c], a2);
    a3 = fmaf(v, w3[c], a3);
  }
  red[wv][0][lane] = a0; red[wv][1][lane] = a1;
  red[wv][2][lane] = a2; red[wv][3][lane] = a3;
  __syncthreads();
  if (wv == 0) {
    float* h5p = ws + (ks ? OFF_H5B : OFF_H5) / 4;
    #pragma unroll
    for (int m = 0; m < 4; ++m) {
      float s = red[0][m][lane] + red[1][m][lane] + red[2][m][lane] + red[3][m][lane];
      h5p[((og * 4 + m) * 25 + pyx) * 64 + lane] = s;
    }
  }
}

__global__ void __launch_bounds__(256) k6_fc1(const float* __restrict__ w,
                                              const float* __restrict__ oo_b, float* ws) {
  const float* h5a = ws + OFF_H5 / 4;
  const float* h5b = ws + OFF_H5B / 4;
  float* h6 = ws + OFF_H6 / 4;
  __shared__ float red[4][4][64];
  int lane = threadIdx.x;
  int wv = __builtin_amdgcn_readfirstlane(threadIdx.y);
  int og = blockIdx.x, ks = blockIdx.y;
  int kb = ks * 156 + (ks < 4 ? ks : 4);
  int kn = 156 + (ks < 4 ? 1 : 0);
  int q = kn >> 2, r = kn & 3;
  int base = __builtin_amdgcn_readfirstlane(kb + wv * q + (wv < r ? wv : r));
  int n = q + (wv < r ? 1 : 0);
  const float* w0 = w + (og * 4 + 0) * 2500;
  const float* w1 = w + (og * 4 + 1) * 2500;
  const float* w2 = w + (og * 4 + 2) * 2500;
  const float* w3 = w + (og * 4 + 3) * 2500;
  float a0 = 0.f, a1 = 0.f, a2 = 0.f, a3 = 0.f;
  #pragma unroll 4
  for (int i = 0; i < n; ++i) {
    int k = base + i;
    float v = fmaxf(h5a[k * 64 + lane] + h5b[k * 64 + lane] + oo_b[k / 25], 0.f);
    a0 = fmaf(v, w0[k], a0);
    a1 = fmaf(v, w1[k], a1);
    a2 = fmaf(v, w2[k], a2);
    a3 = fmaf(v, w3[k], a3);
  }
  red[wv][0][lane] = a0; red[wv][1][lane] = a1;
  red[wv][2][lane] = a2; red[wv][3][lane] = a3;
  __syncthreads();
  if (wv == 0) {
    #pragma unroll
    for (int m = 0; m < 4; ++m) {
      float s = red[0][m][lane] + red[1][m][lane] + red[2][m][lane] + red[3][m][lane];
      atomicAdd(&h6[(og * 4 + m) * 64 + lane], s);
    }
  }
}

__global__ void __launch_bounds__(256) k7_fc2(const float* __restrict__ w,
                                              const float* __restrict__ fc1_b,
                                              const float* __restrict__ bias, float* ws) {
  const float* h6 = ws + OFF_H6 / 4;
  float* h7 = ws + OFF_H7 / 4;
  __shared__ float red[4][64];
  int lane = threadIdx.x & 63, wv = threadIdx.x >> 6;
  int o = blockIdx.x;
  float acc = 0.f;
  int i0 = wv * 30;
  #pragma unroll 5
  for (int i = i0; i < i0 + 30; ++i) {
    float v = fmaxf(h6[i * 64 + lane] + fc1_b[i], 0.f);
    acc = fmaf(v, w[o * 120 + i], acc);
  }
  red[wv][lane] = acc;
  __syncthreads();
  if (threadIdx.x < 64) {
    float s = red[0][lane] + red[1][lane] + red[2][lane] + red[3][lane] + bias[o];
    h7[o * 64 + lane] = fmaxf(s, 0.f);
  }
}

__global__ void __launch_bounds__(256) k8_fc3(const float* __restrict__ w,
                                              const float* __restrict__ bias,
                                              float* out, const float* ws) {
  const float* h7 = ws + OFF_H7 / 4;
  __shared__ float red[4][64];
  int lane = threadIdx.x & 63, wv = threadIdx.x >> 6;
  int o = blockIdx.x;
  float acc = 0.f;
  int i0 = wv * 21;
  #pragma unroll 7
  for (int i = i0; i < i0 + 21; ++i)
    acc = fmaf(h7[i * 64 + lane], w[o * 84 + i], acc);
  red[wv][lane] = acc;
  __syncthreads();
  if (threadIdx.x < 64) {
    float s = red[0][lane] + red[1][lane] + red[2][lane] + red[3][lane] + bias[o];
    out[lane * 10 + o] = s;
  }
}

extern "C" void kernel_launch(void* const* d_in, const int* in_sizes, int n_in,
                              void* d_out, int out_size, void* d_ws, size_t ws_size,
                              hipStream_t stream) {
  const float* x     = (const float*)d_in[0];
  const float* dw1_w = (const float*)d_in[1];
  const float* dw1_b = (const float*)d_in[2];
  const float* pc1_w = (const float*)d_in[3];
  const float* pc1_b = (const float*)d_in[4];
  const float* dw2_w = (const float*)d_in[5];
  const float* dw2_b = (const float*)d_in[6];
  const float* pc2_w = (const float*)d_in[7];
  const float* pc2_b = (const float*)d_in[8];
  const float* oo_w  = (const float*)d_in[9];
  const float* oo_b  = (const float*)d_in[10];
  const float* fc1_w = (const float*)d_in[11];
  const float* fc1_b = (const float*)d_in[12];
  const float* fc2_w = (const float*)d_in[13];
  const float* fc2_b = (const float*)d_in[14];
  const float* fc3_w = (const float*)d_in[15];
  const float* fc3_b = (const float*)d_in[16];
  float* ws = (float*)d_ws;
  float* out = (float*)d_out;

  // Cooperative grid size: cap at 1024 (256 CU x 4 blocks guaranteed by
  // __launch_bounds__(256,4)); query to be safe.
  static int nb = 0;
  if (nb == 0) {
    int per_cu = 0;
    hipError_t e = hipOccupancyMaxActiveBlocksPerMultiprocessor(
        &per_cu, (const void*)mega, 256, 0);
    if (e != hipSuccess || per_cu < 1) per_cu = 4;
    long total = (long)per_cu * 256;
    nb = (int)(total < 1024 ? total : 1024);
    if (nb < 32) nb = 32;
  }

  MegaParams prm;
  prm.dw1_w = dw1_w; prm.dw1_b = dw1_b;
  prm.pc1_w = pc1_w; prm.pc1_b = pc1_b;
  prm.dw2_w = dw2_w; prm.dw2_b = dw2_b;
  prm.pc2_b = pc2_b;
  prm.oo_w = oo_w;   prm.oo_b = oo_b;
  prm.fc1_w = fc1_w; prm.fc1_b = fc1_b;
  prm.fc2_w = fc2_w; prm.fc2_b = fc2_b;
  prm.fc3_w = fc3_w; prm.fc3_b = fc3_b;
  prm.ws = ws; prm.out = out;

  // Setup (incl. barrier-counter zeroing) runs first; stream order syncs it.
  hipLaunchKernelGGL(k0_setup, dim3(235), dim3(256), 0, stream, x, pc2_w, ws);

  void* kargs[] = { &prm };
  hipError_t le = hipLaunchCooperativeKernel((const void*)mega, dim3(nb), dim3(256),
                                             kargs, 0, stream);
  if (le != hipSuccess) {
    // Fallback: original 9-kernel pipeline (k0 already launched above).
    hipLaunchKernelGGL(k1_dw1, dim3(882), dim3(64, 4), 0, stream, dw1_w, dw1_b, ws);
    hipLaunchKernelGGL(k2_pc1, dim3(625), dim3(64, 4), 0, stream, pc1_w, pc1_b, ws);
    hipLaunchKernelGGL(k3_dw2, dim3(1594), dim3(64, 4), 0, stream, dw2_w, dw2_b, ws);
    hipLaunchKernelGGL(k4_pc2, dim3(25, 67), dim3(64, 4), 0, stream, pc2_b, ws);
    hipLaunchKernelGGL(k5_oo, dim3(25, 25, 2), dim3(64, 4), 0, stream, oo_w, ws);
    hipLaunchKernelGGL(k6_fc1, dim3(30, 16), dim3(64, 4), 0, stream, fc1_w, oo_b, ws);
    hipLaunchKernelGGL(k7_fc2, dim3(84), dim3(256), 0, stream, fc2_w, fc1_b, fc2_b, ws);
    hipLaunchKernelGGL(k8_fc3, dim3(10), dim3(256), 0, stream, fc3_w, fc3_b, out, ws);
  }
}

// Round 3
// 232.029 us; speedup vs baseline: 3.7728x; 3.7728x over previous
//
#include <hip/hip_runtime.h>

// ---------------- workspace layout (byte offsets, all 256-aligned) ----------
static constexpr size_t OFF_XT = 0;          // xT  [3][32][32][64] f32   786432 B
static constexpr size_t OFF_H1 = 786432;     // h1  [18][28][28][64]      3612672 B  (dead after k2; reused as h5b)
static constexpr size_t OFF_H2 = 4399104;    // h2  [51][14][14][64]      2558976 B
static constexpr size_t OFF_H3 = 6958080;    // h3  [255][5][5][2][2][64] 6528000 B  (pool-permuted)
static constexpr size_t OFF_H4 = 13486080;   // h4  [515][5][5][64]       3296000 B
static constexpr size_t OFF_H5 = 16782080;   // h5a [2500][64] PARTIAL    640000 B
static constexpr size_t OFF_H5B = OFF_H1;    // h5b [2500][64] PARTIAL    (aliases dead h1)
static constexpr size_t OFF_H6 = 17422080;   // h6T [120][64] PRE-ACT     30720 B (zeroed in k0; atomicAdd in k6)
static constexpr size_t OFF_H7 = 17452800;   // h7T [84][64]              21504 B (unused now; tail keeps h7 in LDS)
static constexpr size_t OFF_M1 = 17474304;   // int src1[51][4]           1024 B
static constexpr size_t OFF_M2 = 17475328;   // Meta2[536]                8704 B
static constexpr size_t OFF_W2 = 17484032;   // float W2T[51][536]        109344 B (TRANSPOSED densified pc2 weights)
// total ~17.6 MB

struct Meta2 { int g; int special; float wj; int valid; };

// slot-group table for k4: 35 wave-groups of <=16 slots, each within one
// contiguous-k class (class bounds 8/64/168/328/536)
__device__ const int g_s0tab[35] = {
  0,
  8, 24, 40, 56,
  64, 80, 96, 112, 128, 144, 160,
  168, 184, 200, 216, 232, 248, 264, 280, 296, 312,
  328, 344, 360, 376, 392, 408, 424, 440, 456, 472, 488, 504, 520
};

// enumerate pc1 groups in build_perm order (tiny: 51 entries, F=6 ncpf=3)
__device__ inline void scan_ijk(int F, int ncpf, int g, int& oi, int& oj, int& ok) {
  int cnt = 0;
  for (int i = 0; i < F; ++i)
    for (int j = 0; j < ncpf; ++j) {
      int ks = (j == 0) ? i : i + 1;
      for (int k = ks; k < F; ++k) {
        if (cnt == g) { oi = i; oj = j; ok = k; return; }
        ++cnt;
      }
    }
  oi = 0; oj = 0; ok = 0;
}

__device__ inline float4 f4fma(float4 v, float w, float4 a) {
  a.x = fmaf(v.x, w, a.x); a.y = fmaf(v.y, w, a.y);
  a.z = fmaf(v.z, w, a.z); a.w = fmaf(v.w, w, a.w);
  return a;
}

// K0: blocks 0..95   : transpose x [64][3][32][32] -> xT [3][32][32][64]
//     block  96      : pc1 gather metadata (51 groups x 3 srcs)
//     blocks 97..203 : pc2 metadata + densified TRANSPOSED W2T, thread per (s,p)
//     blocks 204..233: zero h6 (fc1 atomicAdd accumulator)
__global__ void k0_setup(const float* __restrict__ x, const float* __restrict__ pc2_w,
                         float* ws) {
  int bx = blockIdx.x, tid = threadIdx.x;
  if (bx < 96) {
    __shared__ float t[64][33];
    int c = bx >> 5, y = bx & 31;
    for (int r = 0; r < 8; ++r) {
      int b = r * 8 + (tid >> 5), xx = tid & 31;
      t[b][xx] = x[((b * 3 + c) * 32 + y) * 32 + xx];
    }
    __syncthreads();
    float* xT = ws + OFF_XT / 4;
    for (int r = 0; r < 8; ++r) {
      int xx = r * 4 + (tid >> 6), b = tid & 63;
      xT[((c * 32 + y) * 32 + xx) * 64 + b] = t[b][xx];
    }
  } else if (bx == 96) {
    if (tid < 51) {
      int i, j, k; scan_ijk(6, 3, tid, i, j, k);
      int* src1 = (int*)((char*)ws + OFF_M1);
      for (int p = 0; p < 3; ++p)
        src1[tid * 4 + p] = (p == j) ? (i * 3 + j) : (k * 3 + p);
    }
  } else if (bx < 204) {
    int idx = (bx - 97) * 256 + tid;     // one thread per (s,p), 536*51 = 27336
    if (idx < 536 * 51) {
      int s = idx / 51, p = idx - s * 51;
      int k, base;
      if (s < 8)        { k = 0; base = 0; }
      else if (s < 64)  { k = 1; base = 8; }
      else if (s < 168) { k = 2; base = 64; }
      else if (s < 328) { k = 3; base = 168; }
      else              { k = 4; base = 328; }
      int id2 = s - base;
      int cnt = 51 * k + 1;              // groups using contiguous block k
      Meta2* m2 = (Meta2*)((char*)ws + OFF_M2);
      float* W2T = (float*)((char*)ws + OFF_W2);
      if (id2 < cnt) {
        int i, j;
        if (id2 <= k) { i = id2; j = 0; }
        else { int t2 = id2 - (k + 1); i = t2 / 50; j = t2 - i * 50 + 1; }
        int off = 205 * i - 51 * ((i * (i - 1)) >> 1);
        int g = (j == 0) ? (off + (k - i))
                         : (off + (5 - i) + (j - 1) * (4 - i) + (k - i - 1));
        W2T[p * 536 + s] = (p == j) ? 0.f : pc2_w[g * 51 + p];
        if (p == 0) {
          m2[s].g = g; m2[s].special = i * 51 + j;
          m2[s].wj = pc2_w[g * 51 + j]; m2[s].valid = 1;
        }
      } else {
        W2T[p * 536 + s] = 0.f;
        if (p == 0) { m2[s].g = 0; m2[s].special = 0; m2[s].wj = 0.f; m2[s].valid = 0; }
      }
    }
  } else {
    int idx = (bx - 204) * 256 + tid;    // zero h6: 120*64 = 7680 floats
    if (idx < 7680) (ws + OFF_H6 / 4)[idx] = 0.f;
  }
}

// K1: dw1 5x5, groups=3. FLOAT4 over batch: each wave does 4 consecutive xo.
//     tasks = 18 o x 28 y x 7 xc = 3528. grid(882) block(64,4)
__global__ void __launch_bounds__(256) k1_dw1(const float* __restrict__ w,
                                              const float* __restrict__ bias, float* ws) {
  const float* xT = ws + OFF_XT / 4;
  float* h1 = ws + OFF_H1 / 4;
  int task = blockIdx.x * 4 + __builtin_amdgcn_readfirstlane(threadIdx.y);
  int l = threadIdx.x;
  int sub = l >> 4, b4 = (l & 15) * 4;
  int o = task / 196, rem = task - o * 196;
  int y = rem / 7, xo = (rem - y * 7) * 4 + sub;
  int c = o / 6;
  float bb = bias[o];
  float4 acc = {bb, bb, bb, bb};
  const float* src = xT + ((c * 32 + y) * 32 + xo) * 64 + b4;
  #pragma unroll
  for (int ky = 0; ky < 5; ++ky)
    #pragma unroll
    for (int kx = 0; kx < 5; ++kx) {
      float4 v = *(const float4*)(src + (ky * 32 + kx) * 64);
      acc = f4fma(v, w[o * 25 + ky * 5 + kx], acc);
    }
  *(float4*)(h1 + ((o * 28 + y) * 28 + xo) * 64 + b4) = acc;
}

// K2: pc1 gather+relu+pool, FLOAT4 over batch. 4 pooled positions per wave.
//     tasks = 51 g x 49 chunks = 2499. grid(625) block(64,4), guard.
__global__ void __launch_bounds__(256) k2_pc1(const float* __restrict__ w,
                                              const float* __restrict__ bias, float* ws) {
  const float* h1 = ws + OFF_H1 / 4;
  const int* src1 = (const int*)((const char*)ws + OFF_M1);
  float* h2 = ws + OFF_H2 / 4;
  int task = blockIdx.x * 4 + __builtin_amdgcn_readfirstlane(threadIdx.y);
  if (task >= 2499) return;
  int l = threadIdx.x;
  int sub = l >> 4, b4 = (l & 15) * 4;
  int g = task / 49, pc = task - g * 49;
  int pp = pc * 4 + sub;               // pooled position 0..195
  int py = pp / 14, px = pp - py * 14;
  int s0 = src1[g * 4 + 0], s1 = src1[g * 4 + 1], s2 = src1[g * 4 + 2];
  float w0 = w[g * 3 + 0], w1 = w[g * 3 + 1], w2 = w[g * 3 + 2], bb = bias[g];
  float4 m = {0.f, 0.f, 0.f, 0.f};
  #pragma unroll
  for (int dy = 0; dy < 2; ++dy)
    #pragma unroll
    for (int dx = 0; dx < 2; ++dx) {
      int y = py * 2 + dy, xx = px * 2 + dx;
      float4 a = {bb, bb, bb, bb};
      a = f4fma(*(const float4*)(h1 + ((s0 * 28 + y) * 28 + xx) * 64 + b4), w0, a);
      a = f4fma(*(const float4*)(h1 + ((s1 * 28 + y) * 28 + xx) * 64 + b4), w1, a);
      a = f4fma(*(const float4*)(h1 + ((s2 * 28 + y) * 28 + xx) * 64 + b4), w2, a);
      m.x = fmaxf(m.x, a.x); m.y = fmaxf(m.y, a.y);
      m.z = fmaxf(m.z, a.z); m.w = fmaxf(m.w, a.w);
    }
  *(float4*)(h2 + ((g * 14 + py) * 14 + px) * 64 + b4) = m;
}

// K3: dw2 5x5 groups=51, pool-permuted out, FLOAT4 over batch. 4 positions/wave.
//     tasks = 255 o x 25 chunks = 6375. grid(1594) block(64,4), guard.
__global__ void __launch_bounds__(256) k3_dw2(const float* __restrict__ w,
                                              const float* __restrict__ bias, float* ws) {
  const float* h2 = ws + OFF_H2 / 4;
  float* h3 = ws + OFF_H3 / 4;
  int task = blockIdx.x * 4 + __builtin_amdgcn_readfirstlane(threadIdx.y);
  if (task >= 6375) return;
  int l = threadIdx.x;
  int sub = l >> 4, b4 = (l & 15) * 4;
  int o = task / 25, pc = task - o * 25;
  int p = pc * 4 + sub;                // position 0..99
  int y = p / 10, xo = p - y * 10;
  int c = o / 5;
  float bb = bias[o];
  float4 acc = {bb, bb, bb, bb};
  const float* src = h2 + ((c * 14 + y) * 14 + xo) * 64 + b4;
  #pragma unroll
  for (int ky = 0; ky < 5; ++ky)
    #pragma unroll
    for (int kx = 0; kx < 5; ++kx) {
      float4 v = *(const float4*)(src + (ky * 14 + kx) * 64);
      acc = f4fma(v, w[o * 25 + ky * 5 + kx], acc);
    }
  int py = y >> 1, dy = y & 1, px = xo >> 1, dx = xo & 1;
  *(float4*)(h3 + ((o * 25 + py * 5 + px) * 4 + dy * 2 + dx) * 64 + b4) = acc;
}

// K4 (REWRITTEN): pc2 = dense 51-dot + rank-1 correction, bias+relu+pool.
//     16 slots per wave (was 2) -> h3 read volume 350 MB -> 45 MB.
//     Weights read from transposed W2T[51][536] (16 contiguous floats per p,
//     wave-uniform -> scalar loads). wave-task = (pyx, group); 35 groups x 25
//     pyx = 875 tasks. grid(219) block(64,4), guard. Consecutive waves share
//     pyx and mostly k -> identical h3 stream -> L1 reuse.
__global__ void k4_pc2(const float* __restrict__ bias, float* ws) {
  const float* h3 = ws + OFF_H3 / 4;
  const float* W2T = (const float*)((const char*)ws + OFF_W2);
  const Meta2* m2 = (const Meta2*)((const char*)ws + OFF_M2);
  float* h4 = ws + OFF_H4 / 4;
  int lane = threadIdx.x;
  int wv = __builtin_amdgcn_readfirstlane(threadIdx.y);
  int task = blockIdx.x * 4 + wv;
  if (task >= 875) return;
  int pyx = task / 35, g = task - pyx * 35;
  int s0 = g_s0tab[g];
  int k, cend;
  if (s0 < 8)        { k = 0; cend = 8; }
  else if (s0 < 64)  { k = 1; cend = 64; }
  else if (s0 < 168) { k = 2; cend = 168; }
  else if (s0 < 328) { k = 3; cend = 328; }
  else               { k = 4; cend = 536; }
  int n = cend - s0; if (n > 16) n = 16;

  float acc[16][4];
  #pragma unroll
  for (int m = 0; m < 16; ++m)
    #pragma unroll
    for (int q = 0; q < 4; ++q) acc[m][q] = 0.f;

  const float* hb = h3 + (size_t)(k * 5100 + pyx * 4) * 64 + lane;  // ch stride 6400
  const float* wb = W2T + s0;
  for (int p = 0; p < 51; ++p) {
    float v0 = hb[p * 6400 + 0];
    float v1 = hb[p * 6400 + 64];
    float v2 = hb[p * 6400 + 128];
    float v3 = hb[p * 6400 + 192];
    const float* wr = wb + p * 536;    // 16 contiguous, wave-uniform
    #pragma unroll
    for (int m = 0; m < 16; ++m) {
      float w = wr[m];
      acc[m][0] = fmaf(v0, w, acc[m][0]);
      acc[m][1] = fmaf(v1, w, acc[m][1]);
      acc[m][2] = fmaf(v2, w, acc[m][2]);
      acc[m][3] = fmaf(v3, w, acc[m][3]);
    }
  }

  for (int m = 0; m < 16; ++m) {
    if (m >= n) break;                 // uniform
    Meta2 mm = m2[s0 + m];
    if (!mm.valid) continue;           // uniform
    const float* hs = h3 + (size_t)(mm.special * 100 + pyx * 4) * 64 + lane;
    float bb = bias[mm.g];
    float r0 = fmaf(hs[0],   mm.wj, acc[m][0]) + bb;
    float r1 = fmaf(hs[64],  mm.wj, acc[m][1]) + bb;
    float r2 = fmaf(hs[128], mm.wj, acc[m][2]) + bb;
    float r3 = fmaf(hs[192], mm.wj, acc[m][3]) + bb;
    float r = fmaxf(fmaxf(r0, r1), fmaxf(r2, r3));
    h4[(mm.g * 25 + pyx) * 64 + lane] = fmaxf(r, 0.f);
  }
}

// K5: oo partials (515->100). grid(25,25,2) block(64,4), base scalarized.
__global__ void __launch_bounds__(256) k5_oo(const float* __restrict__ w, float* ws) {
  const float* h4 = ws + OFF_H4 / 4;
  __shared__ float red[4][4][64];
  int lane = threadIdx.x;
  int wv = __builtin_amdgcn_readfirstlane(threadIdx.y);
  int pyx = blockIdx.x, og = blockIdx.y, ks = blockIdx.z;
  int kb = ks ? 258 : 0;                 // K halves: [0,258) / [258,515)
  int kn = ks ? 257 : 258;
  int q = kn >> 2, r = kn & 3;
  int base = __builtin_amdgcn_readfirstlane(kb + wv * q + (wv < r ? wv : r));
  int n = q + (wv < r ? 1 : 0);          // 64..65 iters per wave
  const float* w0 = w + (og * 4 + 0) * 515;
  const float* w1 = w + (og * 4 + 1) * 515;
  const float* w2 = w + (og * 4 + 2) * 515;
  const float* w3 = w + (og * 4 + 3) * 515;
  const float* hp = h4 + pyx * 64 + lane;
  float a0 = 0.f, a1 = 0.f, a2 = 0.f, a3 = 0.f;
  #pragma unroll 4
  for (int i = 0; i < n; ++i) {
    int c = base + i;
    float v = hp[c * 1600];
    a0 = fmaf(v, w0[c], a0);
    a1 = fmaf(v, w1[c], a1);
    a2 = fmaf(v, w2[c], a2);
    a3 = fmaf(v, w3[c], a3);
  }
  red[wv][0][lane] = a0; red[wv][1][lane] = a1;
  red[wv][2][lane] = a2; red[wv][3][lane] = a3;
  __syncthreads();
  if (wv == 0) {
    float* h5p = ws + (ks ? OFF_H5B : OFF_H5) / 4;
    #pragma unroll
    for (int m = 0; m < 4; ++m) {
      float s = red[0][m][lane] + red[1][m][lane] + red[2][m][lane] + red[3][m][lane];
      h5p[((og * 4 + m) * 25 + pyx) * 64 + lane] = s;
    }
  }
}

// K6: fc1 partials. grid(30,32) block(64,4) (k-split widened 16->32 for
//     occupancy/latency), base scalarized; atomicAdd h6.
__global__ void __launch_bounds__(256) k6_fc1(const float* __restrict__ w,
                                              const float* __restrict__ oo_b, float* ws) {
  const float* h5a = ws + OFF_H5 / 4;
  const float* h5b = ws + OFF_H5B / 4;
  float* h6 = ws + OFF_H6 / 4;
  __shared__ float red[4][4][64];
  int lane = threadIdx.x;
  int wv = __builtin_amdgcn_readfirstlane(threadIdx.y);
  int og = blockIdx.x, ks = blockIdx.y;
  int kb = ks * 78 + (ks < 4 ? ks : 4);        // block k-base
  int kn = 78 + (ks < 4 ? 1 : 0);              // block k-count (sums to 2500)
  int q = kn >> 2, r = kn & 3;
  int base = __builtin_amdgcn_readfirstlane(kb + wv * q + (wv < r ? wv : r));
  int n = q + (wv < r ? 1 : 0);                // wave k-count (~20)
  const float* w0 = w + (og * 4 + 0) * 2500;
  const float* w1 = w + (og * 4 + 1) * 2500;
  const float* w2 = w + (og * 4 + 2) * 2500;
  const float* w3 = w + (og * 4 + 3) * 2500;
  float a0 = 0.f, a1 = 0.f, a2 = 0.f, a3 = 0.f;
  #pragma unroll 4
  for (int i = 0; i < n; ++i) {
    int k = base + i;
    float v = fmaxf(h5a[k * 64 + lane] + h5b[k * 64 + lane] + oo_b[k / 25], 0.f);
    a0 = fmaf(v, w0[k], a0);
    a1 = fmaf(v, w1[k], a1);
    a2 = fmaf(v, w2[k], a2);
    a3 = fmaf(v, w3[k], a3);
  }
  red[wv][0][lane] = a0; red[wv][1][lane] = a1;
  red[wv][2][lane] = a2; red[wv][3][lane] = a3;
  __syncthreads();
  if (wv == 0) {
    #pragma unroll
    for (int m = 0; m < 4; ++m) {
      float s = red[0][m][lane] + red[1][m][lane] + red[2][m][lane] + red[3][m][lane];
      atomicAdd(&h6[(og * 4 + m) * 64 + lane], s);
    }
  }
}

// K78 (fc2 + fc3 fused, single block): h6 -> relu -> fc2 -> relu (h7 in LDS)
//     -> fc3 -> out. Saves one launch+boundary vs separate k7/k8.
//     grid(1) block(256).
__global__ void __launch_bounds__(256) k78_tail(const float* __restrict__ fc1_b,
                                                const float* __restrict__ fc2_w,
                                                const float* __restrict__ fc2_b,
                                                const float* __restrict__ fc3_w,
                                                const float* __restrict__ fc3_b,
                                                float* out, const float* ws) {
  __shared__ float h6l[120 * 64];   // 30720 B
  __shared__ float h7l[84 * 64];    // 21504 B  (total 52224 B, single block)
  const float* h6 = ws + OFF_H6 / 4;
  int tid = threadIdx.x;
  int lane = tid & 63;
  int wv = __builtin_amdgcn_readfirstlane(tid >> 6);

  for (int i = tid; i < 7680; i += 256)
    h6l[i] = fmaxf(h6[i] + fc1_b[i >> 6], 0.f);
  __syncthreads();

  // fc2: each wave owns o = wv*21 .. wv*21+20
  for (int j = 0; j < 21; ++j) {
    int o = wv * 21 + j;
    float acc = fc2_b[o];
    #pragma unroll 8
    for (int i = 0; i < 120; ++i)
      acc = fmaf(h6l[i * 64 + lane], fc2_w[o * 120 + i], acc);
    h7l[o * 64 + lane] = fmaxf(acc, 0.f);
  }
  __syncthreads();

  // fc3: o in {wv, wv+4, wv+8} intersect [0,10)
  for (int o = wv; o < 10; o += 4) {
    float acc = fc3_b[o];
    #pragma unroll 7
    for (int i = 0; i < 84; ++i)
      acc = fmaf(h7l[i * 64 + lane], fc3_w[o * 84 + i], acc);
    out[lane * 10 + o] = acc;
  }
}

extern "C" void kernel_launch(void* const* d_in, const int* in_sizes, int n_in,
                              void* d_out, int out_size, void* d_ws, size_t ws_size,
                              hipStream_t stream) {
  const float* x     = (const float*)d_in[0];
  const float* dw1_w = (const float*)d_in[1];
  const float* dw1_b = (const float*)d_in[2];
  const float* pc1_w = (const float*)d_in[3];
  const float* pc1_b = (const float*)d_in[4];
  const float* dw2_w = (const float*)d_in[5];
  const float* dw2_b = (const float*)d_in[6];
  const float* pc2_w = (const float*)d_in[7];
  const float* pc2_b = (const float*)d_in[8];
  const float* oo_w  = (const float*)d_in[9];
  const float* oo_b  = (const float*)d_in[10];
  const float* fc1_w = (const float*)d_in[11];
  const float* fc1_b = (const float*)d_in[12];
  const float* fc2_w = (const float*)d_in[13];
  const float* fc2_b = (const float*)d_in[14];
  const float* fc3_w = (const float*)d_in[15];
  const float* fc3_b = (const float*)d_in[16];
  float* ws = (float*)d_ws;
  float* out = (float*)d_out;

  hipLaunchKernelGGL(k0_setup, dim3(234), dim3(256), 0, stream, x, pc2_w, ws);
  hipLaunchKernelGGL(k1_dw1, dim3(882), dim3(64, 4), 0, stream, dw1_w, dw1_b, ws);
  hipLaunchKernelGGL(k2_pc1, dim3(625), dim3(64, 4), 0, stream, pc1_w, pc1_b, ws);
  hipLaunchKernelGGL(k3_dw2, dim3(1594), dim3(64, 4), 0, stream, dw2_w, dw2_b, ws);
  hipLaunchKernelGGL(k4_pc2, dim3(219), dim3(64, 4), 0, stream, pc2_b, ws);
  hipLaunchKernelGGL(k5_oo, dim3(25, 25, 2), dim3(64, 4), 0, stream, oo_w, ws);
  hipLaunchKernelGGL(k6_fc1, dim3(30, 32), dim3(64, 4), 0, stream, fc1_w, oo_b, ws);
  hipLaunchKernelGGL(k78_tail, dim3(1), dim3(256), 0, stream,
                     fc1_b, fc2_w, fc2_b, fc3_w, fc3_b, out, ws);
}